// Round 14
// baseline (746.091 us; speedup 1.0000x reference)
//
#include <hip/hip_runtime.h>

#define NN 10000
#define EE 80000
#define TT 10

typedef unsigned short u16;
typedef unsigned int u32;
using f32x4  = __attribute__((ext_vector_type(4))) float;
using bf16x8 = __attribute__((ext_vector_type(8))) short;

__device__ __forceinline__ u16 f2bf(float f) {
  union { float f; u32 u; } v; v.f = f;
  return (u16)((v.u + 0x7fffu + ((v.u >> 16) & 1u)) >> 16);   // RNE
}
__device__ __forceinline__ u32 pk2(float lo, float hi) {
  return (u32)f2bf(lo) | ((u32)f2bf(hi) << 16);
}
__device__ __forceinline__ float bflo(u32 v) { union { u32 u; float f; } x; x.u = v << 16; return x.f; }
__device__ __forceinline__ float bfhi(u32 v) { union { u32 u; float f; } x; x.u = v & 0xffff0000u; return x.f; }

// bijective XCD-aware block swizzle (measured neutral, correct)
__device__ __forceinline__ int xcd_swz(int orig, int nwg) {
  int q = nwg >> 3, r = nwg & 7;
  int xcd = orig & 7, idx = orig >> 3;
  return (xcd < r ? xcd * (q + 1) : r * (q + 1) + (xcd - r) * q) + idx;
}

// ===========================================================================
// CSR build (per-launch; deterministic work)
// ===========================================================================

__global__ __launch_bounds__(256) void hist_k(const int* __restrict__ rcv, int* __restrict__ cnt) {
  int e = blockIdx.x * 256 + threadIdx.x;
  if (e < EE) atomicAdd(&cnt[rcv[e]], 1);
}

__global__ __launch_bounds__(1024) void scan_k(const int* __restrict__ cnt,
                                               int* __restrict__ offs, int* __restrict__ curs) {
  __shared__ int ps[1024];
  const int t = threadIdx.x;
  int loc[10], s = 0;
  #pragma unroll
  for (int j = 0; j < 10; ++j) {
    int idx = t * 10 + j;
    int v = (idx < NN) ? cnt[idx] : 0;
    loc[j] = s; s += v;
  }
  ps[t] = s;
  __syncthreads();
  for (int off = 1; off < 1024; off <<= 1) {
    int v = (t >= off) ? ps[t - off] : 0;
    __syncthreads();
    ps[t] += v;
    __syncthreads();
  }
  int pre = (t == 0) ? 0 : ps[t - 1];
  #pragma unroll
  for (int j = 0; j < 10; ++j) {
    int idx = t * 10 + j;
    if (idx < NN) { int o = pre + loc[j]; offs[idx] = o; curs[idx] = o; }
  }
  if (t == 1023) offs[NN] = ps[1023];
}

// also emits receiver-sorted index arrays: rcv_s[p], snd_s[p]
__global__ __launch_bounds__(256) void scatter_k(const int* __restrict__ rcv,
                                                 const int* __restrict__ snd,
                                                 int* __restrict__ curs,
                                                 int* __restrict__ sortpos,
                                                 int* __restrict__ rcv_s,
                                                 int* __restrict__ snd_s) {
  int e = blockIdx.x * 256 + threadIdx.x;
  if (e < EE) {
    int r = rcv[e];
    int p = atomicAdd(&curs[r], 1);
    sortpos[e] = p;
    rcv_s[p] = r;
    snd_s[p] = snd[e];
  }
}

// ===========================================================================
// consolidated weight pre-transpose: ALL W^T conversions in ONE launch.
// ===========================================================================
#define NJOBS 16
struct WAll {
  const float* src[NJOBS];
  u16*         dst[NJOBS];
  int          K[NJOBS];
  int          kpad[NJOBS];
  long         tstr[NJOBS];
  int          start[NJOBS + 1];
};

__global__ __launch_bounds__(256) void wtrans_all_k(WAll ja) {
  __shared__ float tile[32][33];
  const int b = blockIdx.x;
  int j = 0;
  while (j < NJOBS - 1 && b >= ja.start[j + 1]) ++j;
  const int rem = b - ja.start[j];
  if (ja.K[j] > 0) {
    const int K = ja.K[j];
    const int tiles_per_t = (K / 32) * 4;
    const int t  = rem / tiles_per_t;
    const int r2 = rem - t * tiles_per_t;
    const int kt = r2 >> 2, nt = r2 & 3;
    const float* s = ja.src[j] + (size_t)t * ja.tstr[j];
    u16* d = ja.dst[j] + (size_t)t * 128 * K;
    const int r = threadIdx.x >> 5, c = threadIdx.x & 31;
    for (int rr = r; rr < 32; rr += 8)
      tile[rr][c] = s[(size_t)(kt * 32 + rr) * 128 + nt * 32 + c];
    __syncthreads();
    for (int rr = r; rr < 32; rr += 8)
      d[(size_t)(nt * 32 + rr) * K + kt * 32 + c] = f2bf(tile[c][rr]);
  } else {
    const int Kr = ja.kpad[j];
    const int ch = threadIdx.x;
    if (ch < 128)
      for (int k = 0; k < 64; ++k)
        ja.dst[j][ch * 64 + k] = (k < Kr) ? f2bf(ja.src[j][(size_t)k * 128 + ch]) : (u16)0;
  }
}

// ===========================================================================
// unified MFMA MLP3(+LN) kernel: BM rows x 128 ch per block, BK=64
// WSB = W-stage buffers: 2 = double-buffered (champion), 1 = single-buffered
// (msg only: -16 KB LDS -> 3 blocks/CU at +5 barriers; VGPR=64 per round-12)
//   MODE 0 = msg   (receiver-sorted edges; in-block segment-sum -> pooled)
//   MODE 1 = upd   (residual; zero pooled after read; optional U-emit;
//                   optional FUSED DECODER on last iteration)
//   MODE 2 = encn  (out h+h_bf, U-emit)
//   MODE 3 = ence  (out e_bf[sortpos] scatter)
// ===========================================================================
template<int MODE, int KT0, int BM, int WAVES, int MINW, int WSB>
__global__ __launch_bounds__(WAVES * 64, MINW) void mlp3_mfma_k(
    const u16* __restrict__ h_bf, const u16* __restrict__ e_bf,
    const float* __restrict__ h32, const float* __restrict__ pooled,
    const float* __restrict__ feat,
    const int* __restrict__ snd, const int* __restrict__ rcv,
    const int* __restrict__ sortpos,
    const float* __restrict__ Ur_in, const float* __restrict__ Us_in,
    const u16* __restrict__ Wt0, const float* __restrict__ b0,
    const u16* __restrict__ Wt1, const float* __restrict__ b1,
    const u16* __restrict__ Wt2, const float* __restrict__ b2,
    const float* __restrict__ g,  const float* __restrict__ be,
    const u16* __restrict__ Wtr, const u16* __restrict__ Wts,
    const float* __restrict__ b0n,
    float* __restrict__ h_out, u16* __restrict__ hbf_out,
    float* __restrict__ Ur_out, float* __restrict__ Us_out,
    const u16* __restrict__ dWt0, const float* __restrict__ db0,
    const u16* __restrict__ dWt1, const float* __restrict__ db1,
    const float* __restrict__ dW2, const float* __restrict__ db2,
    float* __restrict__ dec_out) {
  constexpr int K0   = KT0 * 64;
  constexpr int THREADS = WAVES * 64;
  constexpr int WN   = WAVES / 2;     // row-tile waves per ch-half
  constexpr int RH   = BM / WN;       // rows per wn slot
  constexpr int NET  = RH / 16;       // 16-row tiles per wave
  constexpr int RPW  = BM / WAVES;    // rows staged per wave (X)
  constexpr int NI   = RPW / 8;       // X staging iterations
  constexpr int CPW  = 128 / WAVES;   // ch rows staged per wave (W)
  constexpr int NIW  = CPW / 8;       // W staging iterations

  __shared__ u16 XS[2][BM * 64];
  __shared__ u16 WS[WSB][128 * 64];
  __shared__ float part_s[2][BM], part_q[2][BM];

  const int tid = threadIdx.x;
  const int lane = tid & 63;
  const int wq = tid >> 6;
  const int wm = wq / WN, wn = wq % WN;
  const int l15 = lane & 15, lq = lane >> 4;
  const int row0 = xcd_swz(blockIdx.x, gridDim.x) * BM;
  const int lr = lane >> 3;
  const int cj = lane & 7;
  const int ch0 = wm * 64 + lq * 4;

  // ---- MODE 0: T14 async preload of SENDER projections (random-access side)
  f32x4 us[4][(MODE == 0) ? NET : 1];
  if constexpr (MODE == 0) {
    #pragma unroll
    for (int et = 0; et < NET; ++et) {
      int ns = snd[row0 + wn * RH + et * 16 + l15];
      #pragma unroll
      for (int ct = 0; ct < 4; ++ct)
        us[ct][et] = *(const f32x4*)(Us_in + (size_t)ns * 128 + ch0 + ct * 16);
    }
  }

  auto load_x = [&](int kt, uint4 v[NI]) {
    #pragma unroll
    for (int i = 0; i < NI; ++i) {
      int q = wq * RPW + i * 8 + lr;
      if constexpr (MODE == 0) {
        v[i] = *(const uint4*)(e_bf + (size_t)(row0 + q) * 128 + kt * 64 + cj * 8);
      } else if constexpr (MODE == 1) {
        int gn = row0 + q;
        if (gn < NN) {
          if (kt < 2) {
            v[i] = *(const uint4*)(h_bf + (size_t)gn * 128 + kt * 64 + cj * 8);
          } else {
            const float* p = pooled + (size_t)gn * 128 + (kt - 2) * 64 + cj * 8;
            float4 a = *(const float4*)p;
            float4 b = *(const float4*)(p + 4);
            v[i].x = pk2(a.x, a.y); v[i].y = pk2(a.z, a.w);
            v[i].z = pk2(b.x, b.y); v[i].w = pk2(b.z, b.w);
          }
        } else v[i] = make_uint4(0, 0, 0, 0);
      } else if constexpr (MODE == 2) {
        int gn = row0 + q;
        float x[8];
        #pragma unroll
        for (int j = 0; j < 8; ++j) {
          int k = cj * 8 + j;
          x[j] = (gn < NN && k < 30) ? feat[(size_t)gn * 30 + k] : 0.f;
        }
        v[i].x = pk2(x[0], x[1]); v[i].y = pk2(x[2], x[3]);
        v[i].z = pk2(x[4], x[5]); v[i].w = pk2(x[6], x[7]);
      } else {
        int ge = row0 + q;
        float x[8];
        #pragma unroll
        for (int j = 0; j < 8; ++j) {
          int k = cj * 8 + j;
          x[j] = (k < 3) ? feat[(size_t)ge * 3 + k] : 0.f;
        }
        v[i].x = pk2(x[0], x[1]); v[i].y = pk2(x[2], x[3]);
        v[i].z = pk2(x[4], x[5]); v[i].w = pk2(x[6], x[7]);
      }
    }
  };
  auto load_w = [&](const u16* Wt, int kstr, int kt, uint4 v[NIW]) {
    #pragma unroll
    for (int i = 0; i < NIW; ++i) {
      int ch = wq * CPW + i * 8 + lr;
      v[i] = *(const uint4*)(Wt + (size_t)ch * kstr + kt * 64 + cj * 8);
    }
  };
  auto stage_x = [&](int buf, const uint4 v[NI]) {
    #pragma unroll
    for (int i = 0; i < NI; ++i) {
      int q = wq * RPW + i * 8 + lr;
      int c = cj ^ (lr & 7);
      *(uint4*)&XS[buf][q * 64 + c * 8] = v[i];
    }
  };
  auto stage_w = [&](int buf, const uint4 v[NIW]) {
    #pragma unroll
    for (int i = 0; i < NIW; ++i) {
      int q = wq * CPW + i * 8 + lr;
      int c = cj ^ (lr & 7);
      *(uint4*)&WS[buf][q * 64 + c * 8] = v[i];
    }
  };

  f32x4 acc[4][NET];
  auto init_acc = [&](const float* b) {
    #pragma unroll
    for (int ct = 0; ct < 4; ++ct) {
      f32x4 bv = {0.f, 0.f, 0.f, 0.f};
      if (b) bv = *(const f32x4*)(b + ch0 + ct * 16);
      #pragma unroll
      for (int et = 0; et < NET; ++et) acc[ct][et] = bv;
    }
  };
  auto compute_tile = [&](const u16* xbuf, const u16* wbuf) {
    #pragma unroll
    for (int k0 = 0; k0 < 2; ++k0) {
      bf16x8 wf[4], xf[NET];
      #pragma unroll
      for (int ct = 0; ct < 4; ++ct) {
        int ch = wm * 64 + ct * 16 + l15;
        wf[ct] = *(const bf16x8*)&wbuf[ch * 64 + (((k0 * 4 + lq) ^ (l15 & 7)) * 8)];
      }
      #pragma unroll
      for (int et = 0; et < NET; ++et) {
        int ed = wn * RH + et * 16 + l15;
        xf[et] = *(const bf16x8*)&xbuf[ed * 64 + (((k0 * 4 + lq) ^ (l15 & 7)) * 8)];
      }
      __builtin_amdgcn_s_setprio(1);
      #pragma unroll
      for (int ct = 0; ct < 4; ++ct)
        #pragma unroll
        for (int et = 0; et < NET; ++et)
          acc[ct][et] = __builtin_amdgcn_mfma_f32_16x16x32_bf16(wf[ct], xf[et], acc[ct][et], 0, 0, 0);
      __builtin_amdgcn_s_setprio(0);
    }
  };
  // one full K=128 layer with X already in XS (both halves), W LDS-staged
  auto layer128 = [&](const u16* Wt, const float* b, uint4 vwl[NIW]) {
    init_acc(b);
    if constexpr (WSB == 2) {
      load_w(Wt, 128, 0, vwl); stage_w(0, vwl);
      __syncthreads();
      for (int kt = 0; kt < 2; ++kt) {
        if (kt < 1) load_w(Wt, 128, 1, vwl);
        compute_tile(XS[kt], WS[kt]);
        if (kt < 1) stage_w(1, vwl);
        __syncthreads();
      }
    } else {
      #pragma unroll 1
      for (int kt = 0; kt < 2; ++kt) {
        load_w(Wt, 128, kt, vwl);
        __syncthreads();      // prior WS readers done; prior XS stores visible
        stage_w(0, vwl);
        __syncthreads();      // WS ready
        compute_tile(XS[kt], WS[0]);
      }
      __syncthreads();        // XS readers done (caller may overwrite XS)
    }
  };
  // write acc (optionally relu) as bf16 into XS[0..1] = [row][128 k], swizzled
  auto store_h = [&](bool relu) {
    #pragma unroll
    for (int ct = 0; ct < 4; ++ct)
      #pragma unroll
      for (int et = 0; et < NET; ++et) {
        float v0 = acc[ct][et][0], v1 = acc[ct][et][1], v2 = acc[ct][et][2], v3 = acc[ct][et][3];
        if (relu) { v0 = fmaxf(v0, 0.f); v1 = fmaxf(v1, 0.f); v2 = fmaxf(v2, 0.f); v3 = fmaxf(v3, 0.f); }
        ushort4 o = {f2bf(v0), f2bf(v1), f2bf(v2), f2bf(v3)};
        int ed = wn * RH + et * 16 + l15;
        int c3 = ct * 2 + (lq >> 1);
        int cs = c3 ^ (l15 & 7);
        *(ushort4*)&XS[wm][ed * 64 + cs * 8 + (lq & 1) * 4] = o;
      }
  };

  uint4 vx[NI], vw[NIW];

  // ---------------- layer 0: K0, KT0 k-tiles ----------------
  if constexpr (MODE == 0) init_acc(nullptr); else init_acc(b0);
  load_x(0, vx); load_w(Wt0, K0, 0, vw);
  stage_x(0, vx); stage_w(0, vw);
  __syncthreads();
  for (int kt = 0; kt < KT0; ++kt) {
    int cur = kt & 1, nxt = cur ^ 1;
    if (kt < KT0 - 1) { load_x(kt + 1, vx); load_w(Wt0, K0, kt + 1, vw); }
    compute_tile(XS[cur], WS[WSB == 2 ? cur : 0]);
    if (kt < KT0 - 1) {
      stage_x(nxt, vx);
      if constexpr (WSB == 2) {
        stage_w(nxt, vw);
        __syncthreads();
      } else {
        __syncthreads();          // WS readers done; XS[nxt] staged
        stage_w(0, vw);
        __syncthreads();          // WS ready
      }
    } else {
      __syncthreads();            // final: XS readers done before store_h
    }
  }
  // MODE 1: zero the pooled rows this block consumed (baseline for next msg iter)
  if constexpr (MODE == 1) {
    float* pz = (float*)pooled;
    #pragma unroll
    for (int i = 0; i < NI; ++i) {
      int gn = row0 + wq * RPW + i * 8 + lr;
      if (gn < NN) {
        float4 z = {0.f, 0.f, 0.f, 0.f};
        #pragma unroll
        for (int kt2 = 0; kt2 < 2; ++kt2) {
          *(float4*)(pz + (size_t)gn * 128 + kt2 * 64 + cj * 8) = z;
          *(float4*)(pz + (size_t)gn * 128 + kt2 * 64 + cj * 8 + 4) = z;
        }
      }
    }
  }
  // msg: add Ur[rcv] (sorted, cache-hot) + preloaded Us (b0 folded into Ur)
  if constexpr (MODE == 0) {
    #pragma unroll
    for (int et = 0; et < NET; ++et) {
      int nr = rcv[row0 + wn * RH + et * 16 + l15];
      #pragma unroll
      for (int ct = 0; ct < 4; ++ct) {
        f32x4 vr = *(const f32x4*)(Ur_in + (size_t)nr * 128 + ch0 + ct * 16);
        acc[ct][et] += vr + us[ct][et];
      }
    }
  }
  store_h(true);          // h1 -> XS[0..1]
  __syncthreads();

  // ---------------- layer 1 / layer 2 ----------------
  layer128(Wt1, b1, vw);
  store_h(true);          // h2 -> XS[0..1]  (WSB1: layer128 ends with barrier)
  __syncthreads();
  layer128(Wt2, b2, vw);

  // ---------------- LayerNorm (fp32, cross-wave over wm halves) ----------------
  float ss[NET], qs[NET];
  #pragma unroll
  for (int et = 0; et < NET; ++et) {
    float s = 0.f, q = 0.f;
    #pragma unroll
    for (int ct = 0; ct < 4; ++ct)
      #pragma unroll
      for (int i = 0; i < 4; ++i) { float v = acc[ct][et][i]; s += v; q += v * v; }
    s += __shfl_xor(s, 16, 64); s += __shfl_xor(s, 32, 64);
    q += __shfl_xor(q, 16, 64); q += __shfl_xor(q, 32, 64);
    ss[et] = s; qs[et] = q;
  }
  if (lane < 16) {
    #pragma unroll
    for (int et = 0; et < NET; ++et) {
      part_s[wm][wn * RH + et * 16 + lane] = ss[et];
      part_q[wm][wn * RH + et * 16 + lane] = qs[et];
    }
  }
  __syncthreads();
  float mean[NET], inv[NET];
  #pragma unroll
  for (int et = 0; et < NET; ++et) {
    int ed = wn * RH + et * 16 + l15;
    float S = part_s[0][ed] + part_s[1][ed];
    float Q = part_q[0][ed] + part_q[1][ed];
    float m = S * (1.f / 128.f);
    float var = Q * (1.f / 128.f) - m * m;
    mean[et] = m; inv[et] = rsqrtf(var + 1e-3f);
  }
  #pragma unroll
  for (int ct = 0; ct < 4; ++ct) {
    f32x4 g4 = *(const f32x4*)(g  + ch0 + ct * 16);
    f32x4 b4 = *(const f32x4*)(be + ch0 + ct * 16);
    #pragma unroll
    for (int et = 0; et < NET; ++et)
      #pragma unroll
      for (int i = 0; i < 4; ++i)
        acc[ct][et][i] = g4[i] * (acc[ct][et][i] - mean[et]) * inv[et] + b4[i];
  }

  if constexpr (MODE == 0) {
    // normalized messages -> XS, then in-block segment-sum -> pooled (h_out)
    store_h(false);
    __syncthreads();
    const int* offs = sortpos;                 // repurposed param
    const int nf = rcv[row0];
    const int nl = rcv[row0 + BM - 1];
    const int cg = tid & 15;                   // 8-channel group
    const int buf = cg >> 3, c3 = cg & 7;
    constexpr int NG = THREADS / 16;
    for (int n = nf + (tid >> 4); n <= nl; n += NG) {
      int s0 = offs[n], s1 = offs[n + 1];
      int a = max(s0, row0) - row0, b = min(s1, row0 + BM) - row0;
      if (a >= b) continue;
      float a8[8] = {0.f, 0.f, 0.f, 0.f, 0.f, 0.f, 0.f, 0.f};
      for (int r = a; r < b; ++r) {
        uint4 v = *(const uint4*)&XS[buf][r * 64 + ((c3 ^ (r & 7)) * 8)];
        a8[0] += bflo(v.x); a8[1] += bfhi(v.x);
        a8[2] += bflo(v.y); a8[3] += bfhi(v.y);
        a8[4] += bflo(v.z); a8[5] += bfhi(v.z);
        a8[6] += bflo(v.w); a8[7] += bfhi(v.w);
      }
      float* pp = h_out + (size_t)n * 128 + cg * 8;   // h_out = pooled
      if (s0 >= row0 && s1 <= row0 + BM) {
        float4 o0 = {a8[0], a8[1], a8[2], a8[3]};
        float4 o1 = {a8[4], a8[5], a8[6], a8[7]};
        *(float4*)pp = o0;
        *(float4*)(pp + 4) = o1;
      } else {
        #pragma unroll
        for (int j = 0; j < 8; ++j) atomicAdd(pp + j, a8[j]);
      }
    }
  } else if constexpr (MODE == 3) {
    // scatter into receiver-sorted order
    int gp[NET];
    #pragma unroll
    for (int et = 0; et < NET; ++et)
      gp[et] = sortpos[row0 + wn * RH + et * 16 + l15];
    #pragma unroll
    for (int ct = 0; ct < 4; ++ct)
      #pragma unroll
      for (int et = 0; et < NET; ++et) {
        f32x4 v = acc[ct][et];
        ushort4 o = {f2bf(v[0]), f2bf(v[1]), f2bf(v[2]), f2bf(v[3])};
        *(ushort4*)(hbf_out + (size_t)gp[et] * 128 + ch0 + ct * 16) = o;
      }
  } else {
    // MODE 1: residual add into acc; MODE 1/2: write h (f32) + h_bf
    #pragma unroll
    for (int ct = 0; ct < 4; ++ct)
      #pragma unroll
      for (int et = 0; et < NET; ++et) {
        int gr = row0 + wn * RH + et * 16 + l15;
        if (gr < NN) {
          if constexpr (MODE == 1)
            acc[ct][et] += *(const f32x4*)(h32 + (size_t)gr * 128 + ch0 + ct * 16);
          f32x4 v = acc[ct][et];
          ushort4 o = {f2bf(v[0]), f2bf(v[1]), f2bf(v[2]), f2bf(v[3])};
          *(f32x4*)(h_out + (size_t)gr * 128 + ch0 + ct * 16) = v;
          *(ushort4*)(hbf_out + (size_t)gr * 128 + ch0 + ct * 16) = o;
        }
      }
    if (Wtr) {
      // U-emit: Ur = h_new@Wtr^T + b0n ; Us = h_new@Wts^T
      store_h(false);     // h_new -> XS[0..1]
      __syncthreads();
      layer128(Wtr, b0n, vw);
      #pragma unroll
      for (int ct = 0; ct < 4; ++ct)
        #pragma unroll
        for (int et = 0; et < NET; ++et) {
          int gr = row0 + wn * RH + et * 16 + l15;
          if (gr < NN)
            *(f32x4*)(Ur_out + (size_t)gr * 128 + ch0 + ct * 16) = acc[ct][et];
        }
      layer128(Wts, nullptr, vw);
      #pragma unroll
      for (int ct = 0; ct < 4; ++ct)
        #pragma unroll
        for (int et = 0; et < NET; ++et) {
          int gr = row0 + wn * RH + et * 16 + l15;
          if (gr < NN)
            *(f32x4*)(Us_out + (size_t)gr * 128 + ch0 + ct * 16) = acc[ct][et];
        }
    } else if (MODE == 1 && dWt0) {
      // FUSED DECODER (last iteration): h_new already in acc
      store_h(false);     // h_new -> XS[0..1]
      __syncthreads();
      layer128(dWt0, db0, vw);        // hd0 = relu(h_new@W0d + b0d)
      store_h(true);
      __syncthreads();
      layer128(dWt1, db1, vw);        // hd1 = relu(hd0@W1d + b1d)
      store_h(true);
      __syncthreads();
      // final 128->3 per-thread dot from XS (bf16)
      if (tid < BM * 3) {
        int r = tid / 3, o = tid - (tid / 3) * 3;
        int gn = row0 + r;
        float a = db2[o];
        #pragma unroll
        for (int c = 0; c < 16; ++c) {
          int buf = c >> 3, c3 = c & 7, cs = c3 ^ (r & 7);
          uint4 v = *(const uint4*)&XS[buf][r * 64 + cs * 8];
          int k = c * 8;
          a = fmaf(bflo(v.x), dW2[(k + 0) * 3 + o], a);
          a = fmaf(bfhi(v.x), dW2[(k + 1) * 3 + o], a);
          a = fmaf(bflo(v.y), dW2[(k + 2) * 3 + o], a);
          a = fmaf(bfhi(v.y), dW2[(k + 3) * 3 + o], a);
          a = fmaf(bflo(v.z), dW2[(k + 4) * 3 + o], a);
          a = fmaf(bfhi(v.z), dW2[(k + 5) * 3 + o], a);
          a = fmaf(bflo(v.w), dW2[(k + 6) * 3 + o], a);
          a = fmaf(bfhi(v.w), dW2[(k + 7) * 3 + o], a);
        }
        if (gn < NN) dec_out[(size_t)gn * 3 + o] = a;
      }
    }
  }
}

// ===========================================================================
extern "C" void kernel_launch(void* const* d_in, const int* in_sizes, int n_in,
                              void* d_out, int out_size, void* d_ws, size_t ws_size,
                              hipStream_t stream) {
  int i = 0;
  const float* node_feat = (const float*)d_in[i++];
  const float* edge_feat = (const float*)d_in[i++];
  const int*   senders   = (const int*)d_in[i++];
  const int*   receivers = (const int*)d_in[i++];
  const float *encn_W0 = (const float*)d_in[i++], *encn_b0 = (const float*)d_in[i++],
              *encn_W1 = (const float*)d_in[i++], *encn_b1 = (const float*)d_in[i++],
              *encn_W2 = (const float*)d_in[i++], *encn_b2 = (const float*)d_in[i++],
              *encn_g  = (const float*)d_in[i++], *encn_be = (const float*)d_in[i++];
  const float *ence_W0 = (const float*)d_in[i++], *ence_b0 = (const float*)d_in[i++],
              *ence_W1 = (const float*)d_in[i++], *ence_b1 = (const float*)d_in[i++],
              *ence_W2 = (const float*)d_in[i++], *ence_b2 = (const float*)d_in[i++],
              *ence_g  = (const float*)d_in[i++], *ence_be = (const float*)d_in[i++];
  const float *msg_W0 = (const float*)d_in[i++], *msg_b0 = (const float*)d_in[i++],
              *msg_W1 = (const float*)d_in[i++], *msg_b1 = (const float*)d_in[i++],
              *msg_W2 = (const float*)d_in[i++], *msg_b2 = (const float*)d_in[i++],
              *msg_g  = (const float*)d_in[i++], *msg_be = (const float*)d_in[i++];
  const float *upd_W0 = (const float*)d_in[i++], *upd_b0 = (const float*)d_in[i++],
              *upd_W1 = (const float*)d_in[i++], *upd_b1 = (const float*)d_in[i++],
              *upd_W2 = (const float*)d_in[i++], *upd_b2 = (const float*)d_in[i++],
              *upd_g  = (const float*)d_in[i++], *upd_be = (const float*)d_in[i++];
  const float *dec_W0 = (const float*)d_in[i++], *dec_b0 = (const float*)d_in[i++],
              *dec_W1 = (const float*)d_in[i++], *dec_b1 = (const float*)d_in[i++],
              *dec_W2 = (const float*)d_in[i++], *dec_b2 = (const float*)d_in[i++];

  // workspace layout (~50 MB)
  char* w = (char*)d_ws;
  float* h      = (float*)w;            w += (size_t)NN * 128 * 4;
  float* pooled = (float*)w;            w += (size_t)NN * 128 * 4;
  float* Ur     = (float*)w;            w += (size_t)NN * 128 * 4;
  float* Us     = (float*)w;            w += (size_t)NN * 128 * 4;
  u16*   h_bf   = (u16*)w;              w += (size_t)NN * 128 * 2;
  u16*   e_bf   = (u16*)w;              w += (size_t)EE * 128 * 2;
  u16*   mWt0e  = (u16*)w;              w += (size_t)10 * 128 * 128 * 2;
  u16*   mWt1   = (u16*)w;              w += (size_t)10 * 128 * 128 * 2;
  u16*   mWt2   = (u16*)w;              w += (size_t)10 * 128 * 128 * 2;
  u16*   pWtr   = (u16*)w;              w += (size_t)10 * 128 * 128 * 2;
  u16*   pWts   = (u16*)w;              w += (size_t)10 * 128 * 128 * 2;
  u16*   uWt0   = (u16*)w;              w += (size_t)10 * 128 * 256 * 2;
  u16*   uWt1   = (u16*)w;              w += (size_t)10 * 128 * 128 * 2;
  u16*   uWt2   = (u16*)w;              w += (size_t)10 * 128 * 128 * 2;
  u16*   nWt0   = (u16*)w;              w += (size_t)128 * 64 * 2;
  u16*   nWt1   = (u16*)w;              w += (size_t)128 * 128 * 2;
  u16*   nWt2   = (u16*)w;              w += (size_t)128 * 128 * 2;
  u16*   eWt0   = (u16*)w;              w += (size_t)128 * 64 * 2;
  u16*   eWt1   = (u16*)w;              w += (size_t)128 * 128 * 2;
  u16*   eWt2   = (u16*)w;              w += (size_t)128 * 128 * 2;
  u16*   dWt0   = (u16*)w;              w += (size_t)128 * 128 * 2;
  u16*   dWt1   = (u16*)w;              w += (size_t)128 * 128 * 2;
  int*   cnt    = (int*)w;              w += (size_t)NN * 4;
  int*   offs   = (int*)w;              w += (size_t)(NN + 1) * 4;
  int*   curs   = (int*)w;              w += (size_t)NN * 4;
  int*   sortp  = (int*)w;              w += (size_t)EE * 4;
  int*   rcv_s  = (int*)w;              w += (size_t)EE * 4;
  int*   snd_s  = (int*)w;              w += (size_t)EE * 4;

  const int NB_N64 = (NN + 63) / 64;     // 157
  const int NB_N32 = (NN + 31) / 32;     // 313
  const int NB_E128 = EE / 128;          // 625
  const int NB_E256 = (EE + 255) / 256;

  // CSR build (once per launch) + zero pooled baseline (iteration 0)
  hipMemsetAsync(cnt, 0, (size_t)NN * 4, stream);
  hipMemsetAsync(pooled, 0, (size_t)NN * 128 * 4, stream);
  hist_k<<<NB_E256, 256, 0, stream>>>(receivers, cnt);
  scan_k<<<1, 1024, 0, stream>>>(cnt, offs, curs);
  scatter_k<<<NB_E256, 256, 0, stream>>>(receivers, senders, curs, sortp, rcv_s, snd_s);

  // ALL weight pre-transposes in ONE launch
  {
    WAll ja;
    const float* srcs[NJOBS] = {
      msg_W0, msg_W0 + 128 * 128, msg_W0 + 256 * 128, msg_W1, msg_W2,
      upd_W0, upd_W1, upd_W2,
      encn_W1, encn_W2, ence_W1, ence_W2, dec_W0, dec_W1,
      encn_W0, ence_W0 };
    u16* dsts[NJOBS] = {
      pWtr, pWts, mWt0e, mWt1, mWt2,
      uWt0, uWt1, uWt2,
      nWt1, nWt2, eWt1, eWt2, dWt0, dWt1,
      nWt0, eWt0 };
    int  Ks[NJOBS]   = {128,128,128,128,128, 256,128,128, 128,128,128,128,128,128, 0,0};
    int  kps[NJOBS]  = {0,0,0,0,0, 0,0,0, 0,0,0,0,0,0, 30,3};
    long tss[NJOBS]  = {384*128,384*128,384*128,128*128,128*128,
                        256*128,128*128,128*128, 0,0,0,0,0,0, 0,0};
    int  nts[NJOBS]  = {10,10,10,10,10, 10,10,10, 1,1,1,1,1,1, 1,1};
    int acc = 0;
    for (int j = 0; j < NJOBS; ++j) {
      ja.src[j] = srcs[j]; ja.dst[j] = dsts[j];
      ja.K[j] = Ks[j]; ja.kpad[j] = kps[j]; ja.tstr[j] = tss[j];
      ja.start[j] = acc;
      acc += (Ks[j] > 0) ? nts[j] * (Ks[j] / 32) * 4 : 1;
    }
    ja.start[NJOBS] = acc;
    wtrans_all_k<<<acc, 256, 0, stream>>>(ja);
  }

  // node encoder (+ U-emit for round 0)
  mlp3_mfma_k<2, 1, 64, 4, 2, 2><<<NB_N64, 256, 0, stream>>>(
      nullptr, nullptr, nullptr, nullptr, node_feat, nullptr, nullptr, nullptr,
      nullptr, nullptr,
      nWt0, encn_b0, nWt1, encn_b1, nWt2, encn_b2, encn_g, encn_be,
      pWtr, pWts, msg_b0,
      h, h_bf, Ur, Us,
      nullptr, nullptr, nullptr, nullptr, nullptr, nullptr, nullptr);
  // edge encoder (scatter into receiver-sorted e_bf)
  mlp3_mfma_k<3, 1, 128, 4, 2, 2><<<NB_E128, 256, 0, stream>>>(
      nullptr, nullptr, nullptr, nullptr, edge_feat, nullptr, nullptr, sortp,
      nullptr, nullptr,
      eWt0, ence_b0, eWt1, ence_b1, eWt2, ence_b2, ence_g, ence_be,
      nullptr, nullptr, nullptr,
      nullptr, e_bf, nullptr, nullptr,
      nullptr, nullptr, nullptr, nullptr, nullptr, nullptr, nullptr);

  for (int t = 0; t < TT; ++t) {
    // msg: 512 threads / 8 waves; WSB=1 (50 KB LDS -> 3 blocks/CU)
    mlp3_mfma_k<0, 2, 128, 8, 4, 1><<<NB_E128, 512, 0, stream>>>(
        nullptr, e_bf, nullptr, nullptr, nullptr, snd_s, rcv_s, offs,
        Ur, Us,
        mWt0e + (size_t)t * 128 * 128, nullptr,
        mWt1  + (size_t)t * 128 * 128, msg_b1 + (size_t)t * 128,
        mWt2  + (size_t)t * 128 * 128, msg_b2 + (size_t)t * 128,
        msg_g + (size_t)t * 128, msg_be + (size_t)t * 128,
        nullptr, nullptr, nullptr,
        pooled, nullptr, nullptr, nullptr,
        nullptr, nullptr, nullptr, nullptr, nullptr, nullptr, nullptr);
    bool last = (t == TT - 1);
    mlp3_mfma_k<1, 4, 32, 4, 4, 2><<<NB_N32, 256, 0, stream>>>(
        h_bf, nullptr, h, pooled, nullptr, nullptr, nullptr, nullptr,
        nullptr, nullptr,
        uWt0 + (size_t)t * 128 * 256, upd_b0 + (size_t)t * 128,
        uWt1 + (size_t)t * 128 * 128, upd_b1 + (size_t)t * 128,
        uWt2 + (size_t)t * 128 * 128, upd_b2 + (size_t)t * 128,
        upd_g + (size_t)t * 128, upd_be + (size_t)t * 128,
        last ? nullptr : (pWtr + (size_t)(t + 1) * 128 * 128),
        last ? nullptr : (pWts + (size_t)(t + 1) * 128 * 128),
        last ? nullptr : (msg_b0 + (size_t)(t + 1) * 128),
        h, h_bf, Ur, Us,
        last ? dWt0 : nullptr, last ? dec_b0 : nullptr,
        last ? dWt1 : nullptr, last ? dec_b1 : nullptr,
        last ? dec_W2 : nullptr, last ? dec_b2 : nullptr,
        last ? (float*)d_out : nullptr);
  }
}

// Round 15
// 606.266 us; speedup vs baseline: 1.2306x; 1.2306x over previous
//
#include <hip/hip_runtime.h>

#define NN 10000
#define EE 80000
#define TT 10

typedef unsigned short u16;
typedef unsigned int u32;
using f32x4  = __attribute__((ext_vector_type(4))) float;
using bf16x8 = __attribute__((ext_vector_type(8))) short;

__device__ __forceinline__ u16 f2bf(float f) {
  union { float f; u32 u; } v; v.f = f;
  return (u16)((v.u + 0x7fffu + ((v.u >> 16) & 1u)) >> 16);   // RNE
}
__device__ __forceinline__ u32 pk2(float lo, float hi) {
  return (u32)f2bf(lo) | ((u32)f2bf(hi) << 16);
}
__device__ __forceinline__ float bflo(u32 v) { union { u32 u; float f; } x; x.u = v << 16; return x.f; }
__device__ __forceinline__ float bfhi(u32 v) { union { u32 u; float f; } x; x.u = v & 0xffff0000u; return x.f; }

// bijective XCD-aware block swizzle (measured neutral, correct)
__device__ __forceinline__ int xcd_swz(int orig, int nwg) {
  int q = nwg >> 3, r = nwg & 7;
  int xcd = orig & 7, idx = orig >> 3;
  return (xcd < r ? xcd * (q + 1) : r * (q + 1) + (xcd - r) * q) + idx;
}

// ===========================================================================
// CSR build (per-launch; deterministic work)
// ===========================================================================

__global__ __launch_bounds__(256) void hist_k(const int* __restrict__ rcv, int* __restrict__ cnt) {
  int e = blockIdx.x * 256 + threadIdx.x;
  if (e < EE) atomicAdd(&cnt[rcv[e]], 1);
}

__global__ __launch_bounds__(1024) void scan_k(const int* __restrict__ cnt,
                                               int* __restrict__ offs, int* __restrict__ curs) {
  __shared__ int ps[1024];
  const int t = threadIdx.x;
  int loc[10], s = 0;
  #pragma unroll
  for (int j = 0; j < 10; ++j) {
    int idx = t * 10 + j;
    int v = (idx < NN) ? cnt[idx] : 0;
    loc[j] = s; s += v;
  }
  ps[t] = s;
  __syncthreads();
  for (int off = 1; off < 1024; off <<= 1) {
    int v = (t >= off) ? ps[t - off] : 0;
    __syncthreads();
    ps[t] += v;
    __syncthreads();
  }
  int pre = (t == 0) ? 0 : ps[t - 1];
  #pragma unroll
  for (int j = 0; j < 10; ++j) {
    int idx = t * 10 + j;
    if (idx < NN) { int o = pre + loc[j]; offs[idx] = o; curs[idx] = o; }
  }
  if (t == 1023) offs[NN] = ps[1023];
}

// also emits receiver-sorted index arrays: rcv_s[p], snd_s[p]
__global__ __launch_bounds__(256) void scatter_k(const int* __restrict__ rcv,
                                                 const int* __restrict__ snd,
                                                 int* __restrict__ curs,
                                                 int* __restrict__ sortpos,
                                                 int* __restrict__ rcv_s,
                                                 int* __restrict__ snd_s) {
  int e = blockIdx.x * 256 + threadIdx.x;
  if (e < EE) {
    int r = rcv[e];
    int p = atomicAdd(&curs[r], 1);
    sortpos[e] = p;
    rcv_s[p] = r;
    snd_s[p] = snd[e];
  }
}

// ===========================================================================
// consolidated weight pre-transpose: ALL W^T conversions in ONE launch.
// job j, K>0 : tiled transpose dst[t][n][k]=bf16(src[t*tstr + k*128 + n])
// job j, K==0: pad variant  dst[n][k<64]= k<kpad ? bf16(src[k*128+n]) : 0
// ===========================================================================
#define NJOBS 16
struct WAll {
  const float* src[NJOBS];
  u16*         dst[NJOBS];
  int          K[NJOBS];
  int          kpad[NJOBS];
  long         tstr[NJOBS];
  int          start[NJOBS + 1];
};

__global__ __launch_bounds__(256) void wtrans_all_k(WAll ja) {
  __shared__ float tile[32][33];
  const int b = blockIdx.x;
  int j = 0;
  while (j < NJOBS - 1 && b >= ja.start[j + 1]) ++j;
  const int rem = b - ja.start[j];
  if (ja.K[j] > 0) {
    const int K = ja.K[j];
    const int tiles_per_t = (K / 32) * 4;
    const int t  = rem / tiles_per_t;
    const int r2 = rem - t * tiles_per_t;
    const int kt = r2 >> 2, nt = r2 & 3;
    const float* s = ja.src[j] + (size_t)t * ja.tstr[j];
    u16* d = ja.dst[j] + (size_t)t * 128 * K;
    const int r = threadIdx.x >> 5, c = threadIdx.x & 31;
    for (int rr = r; rr < 32; rr += 8)
      tile[rr][c] = s[(size_t)(kt * 32 + rr) * 128 + nt * 32 + c];
    __syncthreads();
    for (int rr = r; rr < 32; rr += 8)
      d[(size_t)(nt * 32 + rr) * K + kt * 32 + c] = f2bf(tile[c][rr]);
  } else {
    const int Kr = ja.kpad[j];
    const int ch = threadIdx.x;
    if (ch < 128)
      for (int k = 0; k < 64; ++k)
        ja.dst[j][ch * 64 + k] = (k < Kr) ? f2bf(ja.src[j][(size_t)k * 128 + ch]) : (u16)0;
  }
}

// ===========================================================================
// unified MFMA MLP3(+LN) kernel: BM rows x 128 ch per block, BK=64
//   MODE 0 = msg   (receiver-sorted edges; in-block segment-sum -> pooled)
//   MODE 1 = upd   (residual; zero pooled after read; optional U-emit;
//                   optional FUSED DECODER on last iteration)
//   MODE 2 = encn  (out h+h_bf, U-emit)
//   MODE 3 = ence  (out e_bf[sortpos] scatter)
// ===========================================================================
template<int MODE, int KT0, int BM, int WAVES, int MINW>
__global__ __launch_bounds__(WAVES * 64, MINW) void mlp3_mfma_k(
    const u16* __restrict__ h_bf, const u16* __restrict__ e_bf,
    const float* __restrict__ h32, const float* __restrict__ pooled,
    const float* __restrict__ feat,
    const int* __restrict__ snd, const int* __restrict__ rcv,
    const int* __restrict__ sortpos,
    const float* __restrict__ Ur_in, const float* __restrict__ Us_in,
    const u16* __restrict__ Wt0, const float* __restrict__ b0,
    const u16* __restrict__ Wt1, const float* __restrict__ b1,
    const u16* __restrict__ Wt2, const float* __restrict__ b2,
    const float* __restrict__ g,  const float* __restrict__ be,
    const u16* __restrict__ Wtr, const u16* __restrict__ Wts,
    const float* __restrict__ b0n,
    float* __restrict__ h_out, u16* __restrict__ hbf_out,
    float* __restrict__ Ur_out, float* __restrict__ Us_out,
    const u16* __restrict__ dWt0, const float* __restrict__ db0,
    const u16* __restrict__ dWt1, const float* __restrict__ db1,
    const float* __restrict__ dW2, const float* __restrict__ db2,
    float* __restrict__ dec_out) {
  constexpr int K0   = KT0 * 64;
  constexpr int THREADS = WAVES * 64;
  constexpr int WN   = WAVES / 2;     // row-tile waves per ch-half
  constexpr int RH   = BM / WN;       // rows per wn slot
  constexpr int NET  = RH / 16;       // 16-row tiles per wave
  constexpr int RPW  = BM / WAVES;    // rows staged per wave (X)
  constexpr int NI   = RPW / 8;       // X staging iterations
  constexpr int CPW  = 128 / WAVES;   // ch rows staged per wave (W)
  constexpr int NIW  = CPW / 8;       // W staging iterations

  __shared__ u16 XS[2][BM * 64];
  __shared__ u16 WS[2][128 * 64];
  __shared__ float part_s[2][BM], part_q[2][BM];

  const int tid = threadIdx.x;
  const int lane = tid & 63;
  const int wq = tid >> 6;
  const int wm = wq / WN, wn = wq % WN;
  const int l15 = lane & 15, lq = lane >> 4;
  const int row0 = xcd_swz(blockIdx.x, gridDim.x) * BM;
  const int lr = lane >> 3;
  const int cj = lane & 7;
  const int ch0 = wm * 64 + lq * 4;

  // ---- MODE 0: T14 async preload of SENDER projections (random-access side)
  f32x4 us[4][(MODE == 0) ? NET : 1];
  if constexpr (MODE == 0) {
    #pragma unroll
    for (int et = 0; et < NET; ++et) {
      int ns = snd[row0 + wn * RH + et * 16 + l15];
      #pragma unroll
      for (int ct = 0; ct < 4; ++ct)
        us[ct][et] = *(const f32x4*)(Us_in + (size_t)ns * 128 + ch0 + ct * 16);
    }
  }

  auto load_x = [&](int kt, uint4 v[NI]) {
    #pragma unroll
    for (int i = 0; i < NI; ++i) {
      int q = wq * RPW + i * 8 + lr;
      if constexpr (MODE == 0) {
        v[i] = *(const uint4*)(e_bf + (size_t)(row0 + q) * 128 + kt * 64 + cj * 8);
      } else if constexpr (MODE == 1) {
        int gn = row0 + q;
        if (gn < NN) {
          if (kt < 2) {
            v[i] = *(const uint4*)(h_bf + (size_t)gn * 128 + kt * 64 + cj * 8);
          } else {
            const float* p = pooled + (size_t)gn * 128 + (kt - 2) * 64 + cj * 8;
            float4 a = *(const float4*)p;
            float4 b = *(const float4*)(p + 4);
            v[i].x = pk2(a.x, a.y); v[i].y = pk2(a.z, a.w);
            v[i].z = pk2(b.x, b.y); v[i].w = pk2(b.z, b.w);
          }
        } else v[i] = make_uint4(0, 0, 0, 0);
      } else if constexpr (MODE == 2) {
        int gn = row0 + q;
        float x[8];
        #pragma unroll
        for (int j = 0; j < 8; ++j) {
          int k = cj * 8 + j;
          x[j] = (gn < NN && k < 30) ? feat[(size_t)gn * 30 + k] : 0.f;
        }
        v[i].x = pk2(x[0], x[1]); v[i].y = pk2(x[2], x[3]);
        v[i].z = pk2(x[4], x[5]); v[i].w = pk2(x[6], x[7]);
      } else {
        int ge = row0 + q;
        float x[8];
        #pragma unroll
        for (int j = 0; j < 8; ++j) {
          int k = cj * 8 + j;
          x[j] = (k < 3) ? feat[(size_t)ge * 3 + k] : 0.f;
        }
        v[i].x = pk2(x[0], x[1]); v[i].y = pk2(x[2], x[3]);
        v[i].z = pk2(x[4], x[5]); v[i].w = pk2(x[6], x[7]);
      }
    }
  };
  auto load_w = [&](const u16* Wt, int kstr, int kt, uint4 v[NIW]) {
    #pragma unroll
    for (int i = 0; i < NIW; ++i) {
      int ch = wq * CPW + i * 8 + lr;
      v[i] = *(const uint4*)(Wt + (size_t)ch * kstr + kt * 64 + cj * 8);
    }
  };
  auto stage_x = [&](int buf, const uint4 v[NI]) {
    #pragma unroll
    for (int i = 0; i < NI; ++i) {
      int q = wq * RPW + i * 8 + lr;
      int c = cj ^ (lr & 7);
      *(uint4*)&XS[buf][q * 64 + c * 8] = v[i];
    }
  };
  auto stage_w = [&](int buf, const uint4 v[NIW]) {
    #pragma unroll
    for (int i = 0; i < NIW; ++i) {
      int q = wq * CPW + i * 8 + lr;
      int c = cj ^ (lr & 7);
      *(uint4*)&WS[buf][q * 64 + c * 8] = v[i];
    }
  };

  f32x4 acc[4][NET];
  auto init_acc = [&](const float* b) {
    #pragma unroll
    for (int ct = 0; ct < 4; ++ct) {
      f32x4 bv = {0.f, 0.f, 0.f, 0.f};
      if (b) bv = *(const f32x4*)(b + ch0 + ct * 16);
      #pragma unroll
      for (int et = 0; et < NET; ++et) acc[ct][et] = bv;
    }
  };
  auto compute_tile = [&](const u16* xbuf, const u16* wbuf) {
    #pragma unroll
    for (int k0 = 0; k0 < 2; ++k0) {
      bf16x8 wf[4], xf[NET];
      #pragma unroll
      for (int ct = 0; ct < 4; ++ct) {
        int ch = wm * 64 + ct * 16 + l15;
        wf[ct] = *(const bf16x8*)&wbuf[ch * 64 + (((k0 * 4 + lq) ^ (l15 & 7)) * 8)];
      }
      #pragma unroll
      for (int et = 0; et < NET; ++et) {
        int ed = wn * RH + et * 16 + l15;
        xf[et] = *(const bf16x8*)&xbuf[ed * 64 + (((k0 * 4 + lq) ^ (l15 & 7)) * 8)];
      }
      #pragma unroll
      for (int ct = 0; ct < 4; ++ct)
        #pragma unroll
        for (int et = 0; et < NET; ++et)
          acc[ct][et] = __builtin_amdgcn_mfma_f32_16x16x32_bf16(wf[ct], xf[et], acc[ct][et], 0, 0, 0);
    }
  };
  // one full K=128 layer with X already in XS (both halves), W LDS-staged
  auto layer128 = [&](const u16* Wt, const float* b, uint4 vwl[NIW]) {
    init_acc(b);
    load_w(Wt, 128, 0, vwl); stage_w(0, vwl);
    __syncthreads();
    for (int kt = 0; kt < 2; ++kt) {
      if (kt < 1) load_w(Wt, 128, 1, vwl);
      compute_tile(XS[kt], WS[kt]);
      if (kt < 1) stage_w(1, vwl);
      __syncthreads();
    }
  };
  // write acc (optionally relu) as bf16 into XS[0..1] = [row][128 k], swizzled
  auto store_h = [&](bool relu) {
    #pragma unroll
    for (int ct = 0; ct < 4; ++ct)
      #pragma unroll
      for (int et = 0; et < NET; ++et) {
        float v0 = acc[ct][et][0], v1 = acc[ct][et][1], v2 = acc[ct][et][2], v3 = acc[ct][et][3];
        if (relu) { v0 = fmaxf(v0, 0.f); v1 = fmaxf(v1, 0.f); v2 = fmaxf(v2, 0.f); v3 = fmaxf(v3, 0.f); }
        ushort4 o = {f2bf(v0), f2bf(v1), f2bf(v2), f2bf(v3)};
        int ed = wn * RH + et * 16 + l15;
        int c3 = ct * 2 + (lq >> 1);
        int cs = c3 ^ (l15 & 7);
        *(ushort4*)&XS[wm][ed * 64 + cs * 8 + (lq & 1) * 4] = o;
      }
  };

  uint4 vx[NI], vw[NIW];

  // ---------------- layer 0: K0, KT0 k-tiles ----------------
  if constexpr (MODE == 0) init_acc(nullptr); else init_acc(b0);
  load_x(0, vx); load_w(Wt0, K0, 0, vw);
  stage_x(0, vx); stage_w(0, vw);
  __syncthreads();
  for (int kt = 0; kt < KT0; ++kt) {
    int cur = kt & 1, nxt = cur ^ 1;
    if (kt < KT0 - 1) { load_x(kt + 1, vx); load_w(Wt0, K0, kt + 1, vw); }
    compute_tile(XS[cur], WS[cur]);
    if (kt < KT0 - 1) { stage_x(nxt, vx); stage_w(nxt, vw); }
    __syncthreads();
  }
  // MODE 1: zero the pooled rows this block consumed (baseline for next msg iter)
  if constexpr (MODE == 1) {
    float* pz = (float*)pooled;
    #pragma unroll
    for (int i = 0; i < NI; ++i) {
      int gn = row0 + wq * RPW + i * 8 + lr;
      if (gn < NN) {
        float4 z = {0.f, 0.f, 0.f, 0.f};
        #pragma unroll
        for (int kt2 = 0; kt2 < 2; ++kt2) {
          *(float4*)(pz + (size_t)gn * 128 + kt2 * 64 + cj * 8) = z;
          *(float4*)(pz + (size_t)gn * 128 + kt2 * 64 + cj * 8 + 4) = z;
        }
      }
    }
  }
  // msg: add Ur[rcv] (sorted, cache-hot) + preloaded Us (b0 folded into Ur)
  if constexpr (MODE == 0) {
    #pragma unroll
    for (int et = 0; et < NET; ++et) {
      int nr = rcv[row0 + wn * RH + et * 16 + l15];
      #pragma unroll
      for (int ct = 0; ct < 4; ++ct) {
        f32x4 vr = *(const f32x4*)(Ur_in + (size_t)nr * 128 + ch0 + ct * 16);
        acc[ct][et] += vr + us[ct][et];
      }
    }
  }
  store_h(true);          // h1 -> XS[0..1]
  __syncthreads();

  // ---------------- layer 1 / layer 2 ----------------
  layer128(Wt1, b1, vw);
  store_h(true);          // h2 -> XS[0..1]
  __syncthreads();
  layer128(Wt2, b2, vw);

  // ---------------- LayerNorm (fp32, cross-wave over wm halves) ----------------
  float ss[NET], qs[NET];
  #pragma unroll
  for (int et = 0; et < NET; ++et) {
    float s = 0.f, q = 0.f;
    #pragma unroll
    for (int ct = 0; ct < 4; ++ct)
      #pragma unroll
      for (int i = 0; i < 4; ++i) { float v = acc[ct][et][i]; s += v; q += v * v; }
    s += __shfl_xor(s, 16, 64); s += __shfl_xor(s, 32, 64);
    q += __shfl_xor(q, 16, 64); q += __shfl_xor(q, 32, 64);
    ss[et] = s; qs[et] = q;
  }
  if (lane < 16) {
    #pragma unroll
    for (int et = 0; et < NET; ++et) {
      part_s[wm][wn * RH + et * 16 + lane] = ss[et];
      part_q[wm][wn * RH + et * 16 + lane] = qs[et];
    }
  }
  __syncthreads();
  float mean[NET], inv[NET];
  #pragma unroll
  for (int et = 0; et < NET; ++et) {
    int ed = wn * RH + et * 16 + l15;
    float S = part_s[0][ed] + part_s[1][ed];
    float Q = part_q[0][ed] + part_q[1][ed];
    float m = S * (1.f / 128.f);
    float var = Q * (1.f / 128.f) - m * m;
    mean[et] = m; inv[et] = rsqrtf(var + 1e-3f);
  }
  #pragma unroll
  for (int ct = 0; ct < 4; ++ct) {
    f32x4 g4 = *(const f32x4*)(g  + ch0 + ct * 16);
    f32x4 b4 = *(const f32x4*)(be + ch0 + ct * 16);
    #pragma unroll
    for (int et = 0; et < NET; ++et)
      #pragma unroll
      for (int i = 0; i < 4; ++i)
        acc[ct][et][i] = g4[i] * (acc[ct][et][i] - mean[et]) * inv[et] + b4[i];
  }

  if constexpr (MODE == 0) {
    // normalized messages -> XS, then in-block segment-sum -> pooled (h_out)
    store_h(false);
    __syncthreads();
    const int* offs = sortpos;                 // repurposed param
    const int nf = rcv[row0];
    const int nl = rcv[row0 + BM - 1];
    const int cg = tid & 15;                   // 8-channel group
    const int buf = cg >> 3, c3 = cg & 7;
    constexpr int NG = THREADS / 16;
    for (int n = nf + (tid >> 4); n <= nl; n += NG) {
      int s0 = offs[n], s1 = offs[n + 1];
      int a = max(s0, row0) - row0, b = min(s1, row0 + BM) - row0;
      if (a >= b) continue;
      float a8[8] = {0.f, 0.f, 0.f, 0.f, 0.f, 0.f, 0.f, 0.f};
      for (int r = a; r < b; ++r) {
        uint4 v = *(const uint4*)&XS[buf][r * 64 + ((c3 ^ (r & 7)) * 8)];
        a8[0] += bflo(v.x); a8[1] += bfhi(v.x);
        a8[2] += bflo(v.y); a8[3] += bfhi(v.y);
        a8[4] += bflo(v.z); a8[5] += bfhi(v.z);
        a8[6] += bflo(v.w); a8[7] += bfhi(v.w);
      }
      float* pp = h_out + (size_t)n * 128 + cg * 8;   // h_out = pooled
      if (s0 >= row0 && s1 <= row0 + BM) {
        float4 o0 = {a8[0], a8[1], a8[2], a8[3]};
        float4 o1 = {a8[4], a8[5], a8[6], a8[7]};
        *(float4*)pp = o0;
        *(float4*)(pp + 4) = o1;
      } else {
        #pragma unroll
        for (int j = 0; j < 8; ++j) atomicAdd(pp + j, a8[j]);
      }
    }
  } else if constexpr (MODE == 3) {
    // scatter into receiver-sorted order
    int gp[NET];
    #pragma unroll
    for (int et = 0; et < NET; ++et)
      gp[et] = sortpos[row0 + wn * RH + et * 16 + l15];
    #pragma unroll
    for (int ct = 0; ct < 4; ++ct)
      #pragma unroll
      for (int et = 0; et < NET; ++et) {
        f32x4 v = acc[ct][et];
        ushort4 o = {f2bf(v[0]), f2bf(v[1]), f2bf(v[2]), f2bf(v[3])};
        *(ushort4*)(hbf_out + (size_t)gp[et] * 128 + ch0 + ct * 16) = o;
      }
  } else {
    // MODE 1: residual add into acc; MODE 1/2: write h (f32) + h_bf
    #pragma unroll
    for (int ct = 0; ct < 4; ++ct)
      #pragma unroll
      for (int et = 0; et < NET; ++et) {
        int gr = row0 + wn * RH + et * 16 + l15;
        if (gr < NN) {
          if constexpr (MODE == 1)
            acc[ct][et] += *(const f32x4*)(h32 + (size_t)gr * 128 + ch0 + ct * 16);
          f32x4 v = acc[ct][et];
          ushort4 o = {f2bf(v[0]), f2bf(v[1]), f2bf(v[2]), f2bf(v[3])};
          *(f32x4*)(h_out + (size_t)gr * 128 + ch0 + ct * 16) = v;
          *(ushort4*)(hbf_out + (size_t)gr * 128 + ch0 + ct * 16) = o;
        }
      }
    if (Wtr) {
      // U-emit: Ur = h_new@Wtr^T + b0n ; Us = h_new@Wts^T
      store_h(false);     // h_new -> XS[0..1]
      __syncthreads();
      layer128(Wtr, b0n, vw);
      #pragma unroll
      for (int ct = 0; ct < 4; ++ct)
        #pragma unroll
        for (int et = 0; et < NET; ++et) {
          int gr = row0 + wn * RH + et * 16 + l15;
          if (gr < NN)
            *(f32x4*)(Ur_out + (size_t)gr * 128 + ch0 + ct * 16) = acc[ct][et];
        }
      layer128(Wts, nullptr, vw);
      #pragma unroll
      for (int ct = 0; ct < 4; ++ct)
        #pragma unroll
        for (int et = 0; et < NET; ++et) {
          int gr = row0 + wn * RH + et * 16 + l15;
          if (gr < NN)
            *(f32x4*)(Us_out + (size_t)gr * 128 + ch0 + ct * 16) = acc[ct][et];
        }
    } else if (MODE == 1 && dWt0) {
      // FUSED DECODER (last iteration): h_new already in acc
      store_h(false);     // h_new -> XS[0..1]
      __syncthreads();
      layer128(dWt0, db0, vw);        // hd0 = relu(h_new@W0d + b0d)
      store_h(true);
      __syncthreads();
      layer128(dWt1, db1, vw);        // hd1 = relu(hd0@W1d + b1d)
      store_h(true);
      __syncthreads();
      // final 128->3 per-thread dot from XS (bf16)
      if (tid < BM * 3) {
        int r = tid / 3, o = tid - (tid / 3) * 3;
        int gn = row0 + r;
        float a = db2[o];
        #pragma unroll
        for (int c = 0; c < 16; ++c) {
          int buf = c >> 3, c3 = c & 7, cs = c3 ^ (r & 7);
          uint4 v = *(const uint4*)&XS[buf][r * 64 + cs * 8];
          int k = c * 8;
          a = fmaf(bflo(v.x), dW2[(k + 0) * 3 + o], a);
          a = fmaf(bfhi(v.x), dW2[(k + 1) * 3 + o], a);
          a = fmaf(bflo(v.y), dW2[(k + 2) * 3 + o], a);
          a = fmaf(bfhi(v.y), dW2[(k + 3) * 3 + o], a);
          a = fmaf(bflo(v.z), dW2[(k + 4) * 3 + o], a);
          a = fmaf(bfhi(v.z), dW2[(k + 5) * 3 + o], a);
          a = fmaf(bflo(v.w), dW2[(k + 6) * 3 + o], a);
          a = fmaf(bfhi(v.w), dW2[(k + 7) * 3 + o], a);
        }
        if (gn < NN) dec_out[(size_t)gn * 3 + o] = a;
      }
    }
  }
}

// ===========================================================================
extern "C" void kernel_launch(void* const* d_in, const int* in_sizes, int n_in,
                              void* d_out, int out_size, void* d_ws, size_t ws_size,
                              hipStream_t stream) {
  int i = 0;
  const float* node_feat = (const float*)d_in[i++];
  const float* edge_feat = (const float*)d_in[i++];
  const int*   senders   = (const int*)d_in[i++];
  const int*   receivers = (const int*)d_in[i++];
  const float *encn_W0 = (const float*)d_in[i++], *encn_b0 = (const float*)d_in[i++],
              *encn_W1 = (const float*)d_in[i++], *encn_b1 = (const float*)d_in[i++],
              *encn_W2 = (const float*)d_in[i++], *encn_b2 = (const float*)d_in[i++],
              *encn_g  = (const float*)d_in[i++], *encn_be = (const float*)d_in[i++];
  const float *ence_W0 = (const float*)d_in[i++], *ence_b0 = (const float*)d_in[i++],
              *ence_W1 = (const float*)d_in[i++], *ence_b1 = (const float*)d_in[i++],
              *ence_W2 = (const float*)d_in[i++], *ence_b2 = (const float*)d_in[i++],
              *ence_g  = (const float*)d_in[i++], *ence_be = (const float*)d_in[i++];
  const float *msg_W0 = (const float*)d_in[i++], *msg_b0 = (const float*)d_in[i++],
              *msg_W1 = (const float*)d_in[i++], *msg_b1 = (const float*)d_in[i++],
              *msg_W2 = (const float*)d_in[i++], *msg_b2 = (const float*)d_in[i++],
              *msg_g  = (const float*)d_in[i++], *msg_be = (const float*)d_in[i++];
  const float *upd_W0 = (const float*)d_in[i++], *upd_b0 = (const float*)d_in[i++],
              *upd_W1 = (const float*)d_in[i++], *upd_b1 = (const float*)d_in[i++],
              *upd_W2 = (const float*)d_in[i++], *upd_b2 = (const float*)d_in[i++],
              *upd_g  = (const float*)d_in[i++], *upd_be = (const float*)d_in[i++];
  const float *dec_W0 = (const float*)d_in[i++], *dec_b0 = (const float*)d_in[i++],
              *dec_W1 = (const float*)d_in[i++], *dec_b1 = (const float*)d_in[i++],
              *dec_W2 = (const float*)d_in[i++], *dec_b2 = (const float*)d_in[i++];

  // workspace layout (~50 MB)
  char* w = (char*)d_ws;
  float* h      = (float*)w;            w += (size_t)NN * 128 * 4;
  float* pooled = (float*)w;            w += (size_t)NN * 128 * 4;
  float* Ur     = (float*)w;            w += (size_t)NN * 128 * 4;
  float* Us     = (float*)w;            w += (size_t)NN * 128 * 4;
  u16*   h_bf   = (u16*)w;              w += (size_t)NN * 128 * 2;
  u16*   e_bf   = (u16*)w;              w += (size_t)EE * 128 * 2;
  u16*   mWt0e  = (u16*)w;              w += (size_t)10 * 128 * 128 * 2;
  u16*   mWt1   = (u16*)w;              w += (size_t)10 * 128 * 128 * 2;
  u16*   mWt2   = (u16*)w;              w += (size_t)10 * 128 * 128 * 2;
  u16*   pWtr   = (u16*)w;              w += (size_t)10 * 128 * 128 * 2;
  u16*   pWts   = (u16*)w;              w += (size_t)10 * 128 * 128 * 2;
  u16*   uWt0   = (u16*)w;              w += (size_t)10 * 128 * 256 * 2;
  u16*   uWt1   = (u16*)w;              w += (size_t)10 * 128 * 128 * 2;
  u16*   uWt2   = (u16*)w;              w += (size_t)10 * 128 * 128 * 2;
  u16*   nWt0   = (u16*)w;              w += (size_t)128 * 64 * 2;
  u16*   nWt1   = (u16*)w;              w += (size_t)128 * 128 * 2;
  u16*   nWt2   = (u16*)w;              w += (size_t)128 * 128 * 2;
  u16*   eWt0   = (u16*)w;              w += (size_t)128 * 64 * 2;
  u16*   eWt1   = (u16*)w;              w += (size_t)128 * 128 * 2;
  u16*   eWt2   = (u16*)w;              w += (size_t)128 * 128 * 2;
  u16*   dWt0   = (u16*)w;              w += (size_t)128 * 128 * 2;
  u16*   dWt1   = (u16*)w;              w += (size_t)128 * 128 * 2;
  int*   cnt    = (int*)w;              w += (size_t)NN * 4;
  int*   offs   = (int*)w;              w += (size_t)(NN + 1) * 4;
  int*   curs   = (int*)w;              w += (size_t)NN * 4;
  int*   sortp  = (int*)w;              w += (size_t)EE * 4;
  int*   rcv_s  = (int*)w;              w += (size_t)EE * 4;
  int*   snd_s  = (int*)w;              w += (size_t)EE * 4;

  const int NB_N64 = (NN + 63) / 64;     // 157
  const int NB_N32 = (NN + 31) / 32;     // 313
  const int NB_E128 = EE / 128;          // 625
  const int NB_E256 = (EE + 255) / 256;

  // CSR build (once per launch) + zero pooled baseline (iteration 0)
  hipMemsetAsync(cnt, 0, (size_t)NN * 4, stream);
  hipMemsetAsync(pooled, 0, (size_t)NN * 128 * 4, stream);
  hist_k<<<NB_E256, 256, 0, stream>>>(receivers, cnt);
  scan_k<<<1, 1024, 0, stream>>>(cnt, offs, curs);
  scatter_k<<<NB_E256, 256, 0, stream>>>(receivers, senders, curs, sortp, rcv_s, snd_s);

  // ALL weight pre-transposes in ONE launch
  {
    WAll ja;
    const float* srcs[NJOBS] = {
      msg_W0, msg_W0 + 128 * 128, msg_W0 + 256 * 128, msg_W1, msg_W2,
      upd_W0, upd_W1, upd_W2,
      encn_W1, encn_W2, ence_W1, ence_W2, dec_W0, dec_W1,
      encn_W0, ence_W0 };
    u16* dsts[NJOBS] = {
      pWtr, pWts, mWt0e, mWt1, mWt2,
      uWt0, uWt1, uWt2,
      nWt1, nWt2, eWt1, eWt2, dWt0, dWt1,
      nWt0, eWt0 };
    int  Ks[NJOBS]   = {128,128,128,128,128, 256,128,128, 128,128,128,128,128,128, 0,0};
    int  kps[NJOBS]  = {0,0,0,0,0, 0,0,0, 0,0,0,0,0,0, 30,3};
    long tss[NJOBS]  = {384*128,384*128,384*128,128*128,128*128,
                        256*128,128*128,128*128, 0,0,0,0,0,0, 0,0};
    int  nts[NJOBS]  = {10,10,10,10,10, 10,10,10, 1,1,1,1,1,1, 1,1};
    int acc = 0;
    for (int j = 0; j < NJOBS; ++j) {
      ja.src[j] = srcs[j]; ja.dst[j] = dsts[j];
      ja.K[j] = Ks[j]; ja.kpad[j] = kps[j]; ja.tstr[j] = tss[j];
      ja.start[j] = acc;
      acc += (Ks[j] > 0) ? nts[j] * (Ks[j] / 32) * 4 : 1;
    }
    ja.start[NJOBS] = acc;
    wtrans_all_k<<<acc, 256, 0, stream>>>(ja);
  }

  // node encoder (+ U-emit for round 0)
  mlp3_mfma_k<2, 1, 64, 4, 2><<<NB_N64, 256, 0, stream>>>(
      nullptr, nullptr, nullptr, nullptr, node_feat, nullptr, nullptr, nullptr,
      nullptr, nullptr,
      nWt0, encn_b0, nWt1, encn_b1, nWt2, encn_b2, encn_g, encn_be,
      pWtr, pWts, msg_b0,
      h, h_bf, Ur, Us,
      nullptr, nullptr, nullptr, nullptr, nullptr, nullptr, nullptr);
  // edge encoder (scatter into receiver-sorted e_bf)
  mlp3_mfma_k<3, 1, 128, 4, 2><<<NB_E128, 256, 0, stream>>>(
      nullptr, nullptr, nullptr, nullptr, edge_feat, nullptr, nullptr, sortp,
      nullptr, nullptr,
      eWt0, ence_b0, eWt1, ence_b1, eWt2, ence_b2, ence_g, ence_be,
      nullptr, nullptr, nullptr,
      nullptr, e_bf, nullptr, nullptr,
      nullptr, nullptr, nullptr, nullptr, nullptr, nullptr, nullptr);

  for (int t = 0; t < TT; ++t) {
    // msg: 512 threads / 8 waves; in-block pooling -> pooled
    mlp3_mfma_k<0, 2, 128, 8, 4><<<NB_E128, 512, 0, stream>>>(
        nullptr, e_bf, nullptr, nullptr, nullptr, snd_s, rcv_s, offs,
        Ur, Us,
        mWt0e + (size_t)t * 128 * 128, nullptr,
        mWt1  + (size_t)t * 128 * 128, msg_b1 + (size_t)t * 128,
        mWt2  + (size_t)t * 128 * 128, msg_b2 + (size_t)t * 128,
        msg_g + (size_t)t * 128, msg_be + (size_t)t * 128,
        nullptr, nullptr, nullptr,
        pooled, nullptr, nullptr, nullptr,
        nullptr, nullptr, nullptr, nullptr, nullptr, nullptr, nullptr);
    bool last = (t == TT - 1);
    mlp3_mfma_k<1, 4, 32, 4, 4><<<NB_N32, 256, 0, stream>>>(
        h_bf, nullptr, h, pooled, nullptr, nullptr, nullptr, nullptr,
        nullptr, nullptr,
        uWt0 + (size_t)t * 128 * 256, upd_b0 + (size_t)t * 128,
        uWt1 + (size_t)t * 128 * 128, upd_b1 + (size_t)t * 128,
        uWt2 + (size_t)t * 128 * 128, upd_b2 + (size_t)t * 128,
        upd_g + (size_t)t * 128, upd_be + (size_t)t * 128,
        last ? nullptr : (pWtr + (size_t)(t + 1) * 128 * 128),
        last ? nullptr : (pWts + (size_t)(t + 1) * 128 * 128),
        last ? nullptr : (msg_b0 + (size_t)(t + 1) * 128),
        h, h_bf, Ur, Us,
        last ? dWt0 : nullptr, last ? dec_b0 : nullptr,
        last ? dWt1 : nullptr, last ? dec_b1 : nullptr,
        last ? dec_W2 : nullptr, last ? dec_b2 : nullptr,
        last ? (float*)d_out : nullptr);
  }
}